// Round 6
// baseline (230.178 us; speedup 1.0000x reference)
//
#include <hip/hip_runtime.h>

// MoChA: B=16, S=4096, D=1024, fp32 in/out.
// Outputs: context [B,D] then beta [B,1,S], concatenated flat in d_out.
// Rows s >= k_len[b] have forced outputs (p=0, ec=NEG, beta=0): k/v never read.
// 3 launches: k_energy -> k_seq -> k_ctx (partial + last-arrival fused reduce).

namespace {
constexpr int B = 16, S = 4096, D = 1024;
constexpr int ST = 32;          // s-tiles for context partial sums
constexpr int SL = S / ST;      // 128 s per tile
constexpr float NEGV = -1e9f;

typedef float f4 __attribute__((ext_vector_type(4)));

__device__ __forceinline__ float fast_tanh(float x) {
    float ax = fabsf(x);
    float t = __expf(-2.0f * ax);
    float y = (1.0f - t) * __builtin_amdgcn_rcpf(1.0f + t);
    return copysignf(y, x);
}
__device__ __forceinline__ float fast_sigmoid(float x) {
    return __builtin_amdgcn_rcpf(1.0f + __expf(-x));
}
} // namespace

// ---- kernel 1: energies, strip-mined: one wave owns 16 rows of one (b,i) --
// q+bias and w register-resident; k rows ping-pong double-buffered NT streams.
// Butterfly reduce leaves row sum in all lanes -> lane rl banks row rl; one
// coalesced 16-lane store per wave; sigmoid batched once per wave.
//   i=0 -> p[b,s]  (sigmoid(scale*e + off + noise), masked, end_mask=1)
//   i=1 -> ec[b,s] (masked with NEGV)
__global__ __launch_bounds__(256) void k_energy(
    const float* __restrict__ q, const float* __restrict__ kk,
    const float* __restrict__ v_v, const float* __restrict__ b_mono,
    const float* __restrict__ b_chunk, const float* __restrict__ w_chunk,
    const float* __restrict__ v_g, const float* __restrict__ v_b,
    const float* __restrict__ r, const float* __restrict__ noise,
    const int* __restrict__ k_len,
    float* __restrict__ p_out, float* __restrict__ ec_out)
{
    const int t = threadIdx.x, lane = t & 63, wave = t >> 6;
    const int bi = blockIdx.x >> 6, strip = blockIdx.x & 63;
    const int b = bi >> 1, i = bi & 1;
    const int row0 = strip * 64 + wave * 16;
    const int kl = k_len[b];
    const int nv = min(16, kl - row0);      // valid rows in this wave's strip

    float* outp = (i ? ec_out : p_out) + b * S;
    float myacc = 0.f;
    float scale = 1.f, off0 = 0.f;

    if (nv > 0) {
        const float* qrow = q + (size_t)(b * 2 + i) * D;
        const float* bias = i ? b_chunk : b_mono;
        const float* wv   = i ? w_chunk : v_v;
        f4 qb[4], wr[4];
        #pragma unroll
        for (int it = 0; it < 4; ++it) {
            int d = it * 256 + lane * 4;
            qb[it] = *(const f4*)(qrow + d) + *(const f4*)(bias + d);
            wr[it] = *(const f4*)(wv + d);
        }
        if (i == 0) {   // wave-uniform branch
            float sq = 0.f;
            #pragma unroll
            for (int it = 0; it < 4; ++it)
                sq += wr[it].x * wr[it].x + wr[it].y * wr[it].y
                    + wr[it].z * wr[it].z + wr[it].w * wr[it].w;
            #pragma unroll
            for (int off = 32; off; off >>= 1) sq += __shfl_xor(sq, off);
            scale = v_g[0] / sqrtf(sq);
            off0  = v_b[0] + r[0];
        }

        const float* kbase = kk + ((size_t)(b * 2 + i) * S + row0) * D + lane * 4;
        f4 bufA[4], bufB[4];
        #pragma unroll
        for (int it = 0; it < 4; ++it)
            bufA[it] = __builtin_nontemporal_load((const f4*)(kbase + it * 256));

        auto dot_tanh = [&](const f4* buf) -> float {
            float acc = 0.f;
            #pragma unroll
            for (int it = 0; it < 4; ++it) {
                acc += fast_tanh(qb[it].x + buf[it].x) * wr[it].x
                     + fast_tanh(qb[it].y + buf[it].y) * wr[it].y
                     + fast_tanh(qb[it].z + buf[it].z) * wr[it].z
                     + fast_tanh(qb[it].w + buf[it].w) * wr[it].w;
            }
            #pragma unroll
            for (int off = 32; off; off >>= 1) acc += __shfl_xor(acc, off);
            return acc;
        };

        for (int rl = 0; rl < nv; rl += 2) {
            if (rl + 1 < nv) {
                const float* kn = kbase + (size_t)(rl + 1) * D;
                #pragma unroll
                for (int it = 0; it < 4; ++it)
                    bufB[it] = __builtin_nontemporal_load((const f4*)(kn + it * 256));
            }
            float acc = dot_tanh(bufA);
            if (lane == rl) myacc = acc;
            if (rl + 1 < nv) {
                if (rl + 2 < nv) {
                    const float* kn = kbase + (size_t)(rl + 2) * D;
                    #pragma unroll
                    for (int it = 0; it < 4; ++it)
                        bufA[it] = __builtin_nontemporal_load((const f4*)(kn + it * 256));
                }
                acc = dot_tanh(bufB);
                if (lane == rl + 1) myacc = acc;
            }
        }
    }

    // epilogue: lane l owns row row0+l; one coalesced 16-lane store per wave
    if (lane < 16) {
        const int s = row0 + lane;
        float val;
        if (i == 0) {
            if (lane < nv) {
                float nz = noise[b * S + s];
                val = fast_sigmoid(myacc * scale + off0 + nz);
            } else {
                val = 0.f;
            }
            if (s == kl - 1) val = 1.f;
        } else {
            val = (lane < nv) ? myacc : NEGV;
        }
        outp[s] = val;
    }
}

// ---- kernel 2: per-batch affine scan + chunk windows -> beta ---------------
// 1024 threads, 4 s-values per thread, 4 LDS buffers, 5 barriers total.
// Also zeroes the per-b ticket counters used by the fused k_ctx.
__global__ __launch_bounds__(1024) void k_seq(
    const float* __restrict__ p_in, const float* __restrict__ ec_in,
    const float* __restrict__ prev_att, const int* __restrict__ k_len,
    float* __restrict__ beta_out, unsigned* __restrict__ cnt)
{
    __shared__ float shA[S];   // p  -> ratio
    __shared__ float shB[S];   // pa -> alpha
    __shared__ float shC[S];   // ec
    __shared__ float shD[S];   // exp_e
    __shared__ float wAgg[16], wBgg[16], wExB[16];
    const int b = blockIdx.x;
    const int t = threadIdx.x;
    const int lane = t & 63;
    const int wave = t >> 6;
    const int kl = k_len[b];
    const int s0 = 4 * t;

    if (t == 0) cnt[b] = 0u;    // reset ticket for this call/replay

    // stage p, prev_att, ec
    *(f4*)(shA + s0) = *(const f4*)(p_in + b * S + s0);
    *(f4*)(shB + s0) = *(const f4*)(prev_att + b * S + s0);
    *(f4*)(shC + s0) = *(const f4*)(ec_in + b * S + s0);
    __syncthreads();                                        // (1)

    // B-phase: a[s] = c[s]*a[s-1] + pa[s], c[s] = (s==0)?1:(1-p[s-1])
    float A = 1.f, Bv = 0.f;
    #pragma unroll
    for (int j = 0; j < 4; ++j) {
        int s = s0 + j;
        float c = (s == 0) ? 1.f : (1.f - shA[s - 1]);
        Bv = c * Bv + shB[s];
        A  = c * A;
    }
    float Ai = A, Bi = Bv;
    #pragma unroll
    for (int off = 1; off < 64; off <<= 1) {
        float Ap = __shfl_up(Ai, off);
        float Bp = __shfl_up(Bi, off);
        if (lane >= off) { Bi = Ai * Bp + Bi; Ai = Ai * Ap; }
    }
    if (lane == 63) { wAgg[wave] = Ai; wBgg[wave] = Bi; }
    __syncthreads();                                        // (2)
    if (t == 0) {
        float cB = 0.f;
        #pragma unroll
        for (int w = 0; w < 16; ++w) {
            wExB[w] = cB;
            cB = wAgg[w] * cB + wBgg[w];
        }
    }
    __syncthreads();                                        // (3)
    float eA = __shfl_up(Ai, 1), eB = __shfl_up(Bi, 1);
    if (lane == 0) { eA = 1.f; eB = 0.f; }
    float a = eA * wExB[wave] + eB;      // prefix applied to a0 = 0
    #pragma unroll
    for (int j = 0; j < 4; ++j) {
        int s = s0 + j;
        float c = (s == 0) ? 1.f : (1.f - shA[s - 1]);
        a = c * a + shB[s];
        shB[s] = shA[s] * a;             // alpha (own segment only: safe)
    }
    // no barrier: C1 touches only shC (stable) and shD (virgin)

    // C1: exp_e = (s<kl) ? exp(ec - movmax8(ec)) : 0   -> shD
    {
        f4 out;
        #pragma unroll
        for (int j = 0; j < 4; ++j) {
            int s = s0 + j;
            float m = NEGV;
            #pragma unroll
            for (int w2 = 0; w2 < 8; ++w2) {
                int sw = s - w2;
                m = fmaxf(m, (sw >= 0) ? shC[sw] : NEGV);
            }
            out[j] = (s < kl) ? __expf(shC[s] - m) : 0.f;
        }
        *(f4*)(shD + s0) = out;
    }
    __syncthreads();                                        // (4)

    // C2: ratio = alpha / max(movsum8_back(exp_e), 1e-20)  -> shA
    // (shA's last cross-thread reads were pre-(4); write needs no extra fence)
    {
        f4 out;
        #pragma unroll
        for (int j = 0; j < 4; ++j) {
            int s = s0 + j;
            float den = 0.f;
            #pragma unroll
            for (int w2 = 0; w2 < 8; ++w2) {
                int sw = s - w2;
                if (sw >= 0) den += shD[sw];
            }
            out[j] = shB[s] / fmaxf(den, 1e-20f);
        }
        *(f4*)(shA + s0) = out;
    }
    __syncthreads();                                        // (5)

    // C3: beta = (s<kl) ? exp_e * movsum8_fwd(ratio) : 0
    {
        f4 out;
        #pragma unroll
        for (int j = 0; j < 4; ++j) {
            int s = s0 + j;
            float sum = 0.f;
            #pragma unroll
            for (int w2 = 0; w2 < 8; ++w2) {
                int sw = s + w2;
                if (sw < S) sum += shA[sw];
            }
            out[j] = (s < kl) ? shD[s] * sum : 0.f;
        }
        *(f4*)(beta_out + b * S + s0) = out;
    }
}

// ---- kernel 3: context partials + last-arrival fused reduce ----------------
// beta[s]=0 for s>=kl: stop at the mask boundary (skips v reads).
// Each block writes its partial, then tickets cnt[b]; the 32nd arrival for a
// batch re-reads all 32 partials (L2/L3-hot) in fixed st-order -> ctx[b,:].
// Deterministic: reduce order is the fixed st loop regardless of which block
// performs it.
__global__ __launch_bounds__(256) void k_ctx(
    const float* __restrict__ beta, const float* __restrict__ v,
    const int* __restrict__ k_len, float* __restrict__ partial,
    unsigned* __restrict__ cnt, float* __restrict__ ctx)
{
    __shared__ float sb[SL];
    __shared__ unsigned s_old;
    const int st = blockIdx.x;      // 0..ST-1
    const int b  = blockIdx.y;      // 0..B-1
    const int t  = threadIdx.x;     // d = 4t
    const int kl = k_len[b];
    const int jmax = min(SL, kl - st * SL);
    f4 acc = {0.f, 0.f, 0.f, 0.f};
    if (jmax > 0) {
        if (t < SL) sb[t] = beta[b * S + st * SL + t];
        __syncthreads();
        const float* vp = v + ((size_t)b * S + (size_t)st * SL) * D + 4 * t;
        if (jmax == SL) {
            #pragma unroll 16
            for (int j = 0; j < SL; ++j) {
                f4 vv = __builtin_nontemporal_load((const f4*)(vp + (size_t)j * D));
                acc += sb[j] * vv;
            }
        } else {
            #pragma unroll 4
            for (int j = 0; j < jmax; ++j) {
                f4 vv = __builtin_nontemporal_load((const f4*)(vp + (size_t)j * D));
                acc += sb[j] * vv;
            }
        }
    }
    *(f4*)(partial + ((size_t)(st * B + b)) * D + 4 * t) = acc;

    // ticket: release our partial, count arrivals for batch b
    __threadfence();                 // each thread's store ordered device-wide
    __syncthreads();                 // all 256 threads' stores done
    if (t == 0)
        s_old = __hip_atomic_fetch_add(&cnt[b], 1u, __ATOMIC_ACQ_REL,
                                       __HIP_MEMORY_SCOPE_AGENT);
    __syncthreads();
    if (s_old == ST - 1) {           // we are the last block for batch b
        f4 acc2 = {0.f, 0.f, 0.f, 0.f};
        #pragma unroll 8
        for (int stt = 0; stt < ST; ++stt)
            acc2 += *(const f4*)(partial + ((size_t)(stt * B + b)) * D + 4 * t);
        *(f4*)(ctx + (size_t)b * D + 4 * t) = acc2;
    }
}

extern "C" void kernel_launch(void* const* d_in, const int* in_sizes, int n_in,
                              void* d_out, int out_size, void* d_ws, size_t ws_size,
                              hipStream_t stream) {
    const float* q        = (const float*)d_in[0];
    const float* k        = (const float*)d_in[1];
    const float* v        = (const float*)d_in[2];
    const float* prev_att = (const float*)d_in[3];
    const float* noise    = (const float*)d_in[4];
    const float* b_mono   = (const float*)d_in[5];
    const float* v_v      = (const float*)d_in[6];
    const float* v_g      = (const float*)d_in[7];
    const float* v_b      = (const float*)d_in[8];
    const float* r        = (const float*)d_in[9];
    const float* b_chunk  = (const float*)d_in[10];
    const float* w_chunk  = (const float*)d_in[11];
    const int*   k_len    = (const int*)d_in[12];

    float* out      = (float*)d_out;
    float* ctx_out  = out;            // [B,D]
    float* beta_out = out + B * D;    // [B,1,S]

    float* ws       = (float*)d_ws;
    float* p_arr    = ws;                     // B*S
    float* ec_arr   = p_arr + B * S;          // B*S
    float* partial  = ec_arr + B * S;         // ST*B*D
    unsigned* cnt   = (unsigned*)(partial + (size_t)ST * B * D);  // B

    k_energy<<<B * 2 * 64, 256, 0, stream>>>(
        q, k, v_v, b_mono, b_chunk, w_chunk, v_g, v_b, r, noise, k_len,
        p_arr, ec_arr);
    k_seq<<<B, 1024, 0, stream>>>(p_arr, ec_arr, prev_att, k_len, beta_out, cnt);
    dim3 g3(ST, B);
    k_ctx<<<g3, 256, 0, stream>>>(beta_out, v, k_len, partial, cnt, ctx_out);
}

// Round 7
// 120.102 us; speedup vs baseline: 1.9165x; 1.9165x over previous
//
#include <hip/hip_runtime.h>

// MoChA: B=16, S=4096, D=1024, fp32 in/out.
// Outputs: context [B,D] then beta [B,1,S], concatenated flat in d_out.
// Rows s >= k_len[b] have forced outputs (p=0, ec=NEG, beta=0): k/v never read.
// NOTE (round 6 lesson): do NOT fuse the partial reduce via device-scope
// atomics/fences — cross-XCD coherence traffic cost ~108 us on this kernel.

namespace {
constexpr int B = 16, S = 4096, D = 1024;
constexpr int ST = 32;          // s-tiles for context partial sums
constexpr int SL = S / ST;      // 128 s per tile
constexpr float NEGV = -1e9f;

typedef float f4 __attribute__((ext_vector_type(4)));

__device__ __forceinline__ float fast_tanh(float x) {
    float ax = fabsf(x);
    float t = __expf(-2.0f * ax);
    float y = (1.0f - t) * __builtin_amdgcn_rcpf(1.0f + t);
    return copysignf(y, x);
}
__device__ __forceinline__ float fast_sigmoid(float x) {
    return __builtin_amdgcn_rcpf(1.0f + __expf(-x));
}
} // namespace

// ---- kernel 1: energies, strip-mined: one wave owns 16 rows of one (b,i) --
// q+bias and w register-resident; k rows ping-pong double-buffered NT streams.
// Butterfly reduce leaves row sum in all lanes -> lane rl banks row rl; one
// coalesced 16-lane store per wave; sigmoid batched once per wave.
//   i=0 -> p[b,s]  (sigmoid(scale*e + off + noise), masked, end_mask=1)
//   i=1 -> ec[b,s] (masked with NEGV)
__global__ __launch_bounds__(256) void k_energy(
    const float* __restrict__ q, const float* __restrict__ kk,
    const float* __restrict__ v_v, const float* __restrict__ b_mono,
    const float* __restrict__ b_chunk, const float* __restrict__ w_chunk,
    const float* __restrict__ v_g, const float* __restrict__ v_b,
    const float* __restrict__ r, const float* __restrict__ noise,
    const int* __restrict__ k_len,
    float* __restrict__ p_out, float* __restrict__ ec_out)
{
    const int t = threadIdx.x, lane = t & 63, wave = t >> 6;
    const int bi = blockIdx.x >> 6, strip = blockIdx.x & 63;
    const int b = bi >> 1, i = bi & 1;
    const int row0 = strip * 64 + wave * 16;
    const int kl = k_len[b];
    const int nv = min(16, kl - row0);      // valid rows in this wave's strip

    float* outp = (i ? ec_out : p_out) + b * S;
    float myacc = 0.f;
    float scale = 1.f, off0 = 0.f;

    if (nv > 0) {
        const float* qrow = q + (size_t)(b * 2 + i) * D;
        const float* bias = i ? b_chunk : b_mono;
        const float* wv   = i ? w_chunk : v_v;
        f4 qb[4], wr[4];
        #pragma unroll
        for (int it = 0; it < 4; ++it) {
            int d = it * 256 + lane * 4;
            qb[it] = *(const f4*)(qrow + d) + *(const f4*)(bias + d);
            wr[it] = *(const f4*)(wv + d);
        }
        if (i == 0) {   // wave-uniform branch
            float sq = 0.f;
            #pragma unroll
            for (int it = 0; it < 4; ++it)
                sq += wr[it].x * wr[it].x + wr[it].y * wr[it].y
                    + wr[it].z * wr[it].z + wr[it].w * wr[it].w;
            #pragma unroll
            for (int off = 32; off; off >>= 1) sq += __shfl_xor(sq, off);
            scale = v_g[0] / sqrtf(sq);
            off0  = v_b[0] + r[0];
        }

        const float* kbase = kk + ((size_t)(b * 2 + i) * S + row0) * D + lane * 4;
        f4 bufA[4], bufB[4];
        #pragma unroll
        for (int it = 0; it < 4; ++it)
            bufA[it] = __builtin_nontemporal_load((const f4*)(kbase + it * 256));

        auto dot_tanh = [&](const f4* buf) -> float {
            float acc = 0.f;
            #pragma unroll
            for (int it = 0; it < 4; ++it) {
                acc += fast_tanh(qb[it].x + buf[it].x) * wr[it].x
                     + fast_tanh(qb[it].y + buf[it].y) * wr[it].y
                     + fast_tanh(qb[it].z + buf[it].z) * wr[it].z
                     + fast_tanh(qb[it].w + buf[it].w) * wr[it].w;
            }
            #pragma unroll
            for (int off = 32; off; off >>= 1) acc += __shfl_xor(acc, off);
            return acc;
        };

        for (int rl = 0; rl < nv; rl += 2) {
            if (rl + 1 < nv) {
                const float* kn = kbase + (size_t)(rl + 1) * D;
                #pragma unroll
                for (int it = 0; it < 4; ++it)
                    bufB[it] = __builtin_nontemporal_load((const f4*)(kn + it * 256));
            }
            float acc = dot_tanh(bufA);
            if (lane == rl) myacc = acc;
            if (rl + 1 < nv) {
                if (rl + 2 < nv) {
                    const float* kn = kbase + (size_t)(rl + 2) * D;
                    #pragma unroll
                    for (int it = 0; it < 4; ++it)
                        bufA[it] = __builtin_nontemporal_load((const f4*)(kn + it * 256));
                }
                acc = dot_tanh(bufB);
                if (lane == rl + 1) myacc = acc;
            }
        }
    }

    // epilogue: lane l owns row row0+l; one coalesced 16-lane store per wave
    if (lane < 16) {
        const int s = row0 + lane;
        float val;
        if (i == 0) {
            if (lane < nv) {
                float nz = noise[b * S + s];
                val = fast_sigmoid(myacc * scale + off0 + nz);
            } else {
                val = 0.f;
            }
            if (s == kl - 1) val = 1.f;
        } else {
            val = (lane < nv) ? myacc : NEGV;
        }
        outp[s] = val;
    }
}

// ---- kernel 2: per-batch affine scan + chunk windows -> beta ---------------
// 1024 threads, 4 s-values per thread, 4 LDS buffers, 5 barriers total.
__global__ __launch_bounds__(1024) void k_seq(
    const float* __restrict__ p_in, const float* __restrict__ ec_in,
    const float* __restrict__ prev_att, const int* __restrict__ k_len,
    float* __restrict__ beta_out)
{
    __shared__ float shA[S];   // p  -> ratio
    __shared__ float shB[S];   // pa -> alpha
    __shared__ float shC[S];   // ec
    __shared__ float shD[S];   // exp_e
    __shared__ float wAgg[16], wBgg[16], wExB[16];
    const int b = blockIdx.x;
    const int t = threadIdx.x;
    const int lane = t & 63;
    const int wave = t >> 6;
    const int kl = k_len[b];
    const int s0 = 4 * t;

    // stage p, prev_att, ec
    *(f4*)(shA + s0) = *(const f4*)(p_in + b * S + s0);
    *(f4*)(shB + s0) = *(const f4*)(prev_att + b * S + s0);
    *(f4*)(shC + s0) = *(const f4*)(ec_in + b * S + s0);
    __syncthreads();                                        // (1)

    // B-phase: a[s] = c[s]*a[s-1] + pa[s], c[s] = (s==0)?1:(1-p[s-1])
    float A = 1.f, Bv = 0.f;
    #pragma unroll
    for (int j = 0; j < 4; ++j) {
        int s = s0 + j;
        float c = (s == 0) ? 1.f : (1.f - shA[s - 1]);
        Bv = c * Bv + shB[s];
        A  = c * A;
    }
    float Ai = A, Bi = Bv;
    #pragma unroll
    for (int off = 1; off < 64; off <<= 1) {
        float Ap = __shfl_up(Ai, off);
        float Bp = __shfl_up(Bi, off);
        if (lane >= off) { Bi = Ai * Bp + Bi; Ai = Ai * Ap; }
    }
    if (lane == 63) { wAgg[wave] = Ai; wBgg[wave] = Bi; }
    __syncthreads();                                        // (2)
    if (t == 0) {
        float cB = 0.f;
        #pragma unroll
        for (int w = 0; w < 16; ++w) {
            wExB[w] = cB;
            cB = wAgg[w] * cB + wBgg[w];
        }
    }
    __syncthreads();                                        // (3)
    float eA = __shfl_up(Ai, 1), eB = __shfl_up(Bi, 1);
    if (lane == 0) { eA = 1.f; eB = 0.f; }
    float a = eA * wExB[wave] + eB;      // prefix applied to a0 = 0
    #pragma unroll
    for (int j = 0; j < 4; ++j) {
        int s = s0 + j;
        float c = (s == 0) ? 1.f : (1.f - shA[s - 1]);
        a = c * a + shB[s];
        shB[s] = shA[s] * a;             // alpha (own segment only: safe)
    }
    // no barrier: C1 touches only shC (stable) and shD (virgin)

    // C1: exp_e = (s<kl) ? exp(ec - movmax8(ec)) : 0   -> shD
    {
        f4 out;
        #pragma unroll
        for (int j = 0; j < 4; ++j) {
            int s = s0 + j;
            float m = NEGV;
            #pragma unroll
            for (int w2 = 0; w2 < 8; ++w2) {
                int sw = s - w2;
                m = fmaxf(m, (sw >= 0) ? shC[sw] : NEGV);
            }
            out[j] = (s < kl) ? __expf(shC[s] - m) : 0.f;
        }
        *(f4*)(shD + s0) = out;
    }
    __syncthreads();                                        // (4)

    // C2: ratio = alpha / max(movsum8_back(exp_e), 1e-20)  -> shA
    // (shA's last cross-thread reads were pre-(4); write needs no extra fence)
    {
        f4 out;
        #pragma unroll
        for (int j = 0; j < 4; ++j) {
            int s = s0 + j;
            float den = 0.f;
            #pragma unroll
            for (int w2 = 0; w2 < 8; ++w2) {
                int sw = s - w2;
                if (sw >= 0) den += shD[sw];
            }
            out[j] = shB[s] / fmaxf(den, 1e-20f);
        }
        *(f4*)(shA + s0) = out;
    }
    __syncthreads();                                        // (5)

    // C3: beta = (s<kl) ? exp_e * movsum8_fwd(ratio) : 0
    {
        f4 out;
        #pragma unroll
        for (int j = 0; j < 4; ++j) {
            int s = s0 + j;
            float sum = 0.f;
            #pragma unroll
            for (int w2 = 0; w2 < 8; ++w2) {
                int sw = s + w2;
                if (sw < S) sum += shA[sw];
            }
            out[j] = (s < kl) ? shD[s] * sum : 0.f;
        }
        *(f4*)(beta_out + b * S + s0) = out;
    }
}

// ---- kernel 3: context partial sums over s-tiles (float4 per thread) -------
// beta[s]=0 for s>=kl: stop at the mask boundary (skips v reads).
__global__ __launch_bounds__(256) void k_ctx_partial(
    const float* __restrict__ beta, const float* __restrict__ v,
    const int* __restrict__ k_len, float* __restrict__ partial)
{
    __shared__ float sb[SL];
    const int st = blockIdx.x;      // 0..ST-1
    const int b  = blockIdx.y;      // 0..B-1
    const int t  = threadIdx.x;     // d = 4t
    const int kl = k_len[b];
    const int jmax = min(SL, kl - st * SL);
    f4 acc = {0.f, 0.f, 0.f, 0.f};
    if (jmax > 0) {
        if (t < SL) sb[t] = beta[b * S + st * SL + t];
        __syncthreads();
        const float* vp = v + ((size_t)b * S + (size_t)st * SL) * D + 4 * t;
        if (jmax == SL) {
            #pragma unroll 16
            for (int j = 0; j < SL; ++j) {
                f4 vv = __builtin_nontemporal_load((const f4*)(vp + (size_t)j * D));
                acc += sb[j] * vv;
            }
        } else {
            #pragma unroll 4
            for (int j = 0; j < jmax; ++j) {
                f4 vv = __builtin_nontemporal_load((const f4*)(vp + (size_t)j * D));
                acc += sb[j] * vv;
            }
        }
    }
    *(f4*)(partial + ((size_t)(st * B + b)) * D + 4 * t) = acc;
}

// ---- kernel 4: deterministic reduce of partials ----------------------------
__global__ __launch_bounds__(256) void k_ctx_reduce(
    const float* __restrict__ partial, float* __restrict__ ctx)
{
    int idx = blockIdx.x * 256 + threadIdx.x;   // b*D + d
    float acc = 0.f;
    #pragma unroll
    for (int stt = 0; stt < ST; ++stt)
        acc += partial[(size_t)stt * (B * D) + idx];
    ctx[idx] = acc;
}

extern "C" void kernel_launch(void* const* d_in, const int* in_sizes, int n_in,
                              void* d_out, int out_size, void* d_ws, size_t ws_size,
                              hipStream_t stream) {
    const float* q        = (const float*)d_in[0];
    const float* k        = (const float*)d_in[1];
    const float* v        = (const float*)d_in[2];
    const float* prev_att = (const float*)d_in[3];
    const float* noise    = (const float*)d_in[4];
    const float* b_mono   = (const float*)d_in[5];
    const float* v_v      = (const float*)d_in[6];
    const float* v_g      = (const float*)d_in[7];
    const float* v_b      = (const float*)d_in[8];
    const float* r        = (const float*)d_in[9];
    const float* b_chunk  = (const float*)d_in[10];
    const float* w_chunk  = (const float*)d_in[11];
    const int*   k_len    = (const int*)d_in[12];

    float* out      = (float*)d_out;
    float* ctx_out  = out;            // [B,D]
    float* beta_out = out + B * D;    // [B,1,S]

    float* ws       = (float*)d_ws;
    float* p_arr    = ws;                     // B*S
    float* ec_arr   = p_arr + B * S;          // B*S
    float* partial  = ec_arr + B * S;         // ST*B*D

    k_energy<<<B * 2 * 64, 256, 0, stream>>>(
        q, k, v_v, b_mono, b_chunk, w_chunk, v_g, v_b, r, noise, k_len,
        p_arr, ec_arr);
    k_seq<<<B, 1024, 0, stream>>>(p_arr, ec_arr, prev_att, k_len, beta_out);
    dim3 g3(ST, B);
    k_ctx_partial<<<g3, 256, 0, stream>>>(beta_out, v, k_len, partial);
    k_ctx_reduce<<<(B * D) / 256, 256, 0, stream>>>(partial, ctx_out);
}